// Round 1
// 1075.422 us; speedup vs baseline: 1.0029x; 1.0029x over previous
//
#include <hip/hip_runtime.h>

#define DIM 2048
#define INTER 1408
#define NE 15
#define T_TOKENS 4096
#define NROUTED (T_TOKENS * 2)      // 8192 routed slots
#define NSLOT (NROUTED + T_TOKENS)  // + 4096 shared = 12288

using short8 = __attribute__((ext_vector_type(8))) short;
using f32x4  = __attribute__((ext_vector_type(4))) float;

__device__ inline unsigned short f2bf(float f) {
    return (unsigned short)((__float_as_uint(f) + 0x8000u) >> 16);
}
__device__ inline unsigned pk2bf(unsigned a, unsigned b) {
    // pack two fp32 (bit patterns) -> two bf16 (round-half-up), one v_perm
    return __builtin_amdgcn_perm(b + 0x8000u, a + 0x8000u, 0x07060302u);
}
__device__ inline uint4 cvt8(float4 f0, float4 f1) {
    uint4 r;
    r.x = pk2bf(__float_as_uint(f0.x), __float_as_uint(f0.y));
    r.y = pk2bf(__float_as_uint(f0.z), __float_as_uint(f0.w));
    r.z = pk2bf(__float_as_uint(f1.x), __float_as_uint(f1.y));
    r.w = pk2bf(__float_as_uint(f1.z), __float_as_uint(f1.w));
    return r;
}
// async global->LDS, 16B per lane, dest = wave-uniform base + lane*16
__device__ inline void gll16(const void* g, void* l) {
    __builtin_amdgcn_global_load_lds(
        (const __attribute__((address_space(1))) unsigned int*)g,
        (__attribute__((address_space(3))) unsigned int*)l, 16, 0, 0);
}

// ---------------- generic fp32 -> bf16 (8 elems/thread) ----------------
__global__ void cvt_bf16_kernel(const float* __restrict__ src, unsigned short* __restrict__ dst) {
    size_t i = ((size_t)blockIdx.x * 256 + threadIdx.x) * 8;
    float4 a = *(const float4*)(src + i);
    float4 b = *(const float4*)(src + i + 4);
    *(uint4*)(dst + i) = cvt8(a, b);
}

// ---------------- x -> bf16 (old path) ----------------
__global__ void cvt_x_kernel(const float* __restrict__ x, unsigned short* __restrict__ xb) {
    int i = (blockIdx.x * 256 + threadIdx.x) * 4;
    float4 v = *(const float4*)(x + i);
    ushort4 o;
    o.x = f2bf(v.x); o.y = f2bf(v.y); o.z = f2bf(v.z); o.w = f2bf(v.w);
    *(ushort4*)(xb + i) = o;
}

// ---------------- gating: softmax over 15, top-2 ----------------
__global__ void gate_kernel(const float* __restrict__ x, const float* __restrict__ gw,
                            int* __restrict__ tk_idx, float* __restrict__ tk_w,
                            int* __restrict__ cnt) {
    int tok = blockIdx.x;
    int lane = threadIdx.x; // 64 threads
    const float* xr = x + (size_t)tok * DIM;
    float s[NE];
#pragma unroll
    for (int e = 0; e < NE; e++) s[e] = 0.f;
    for (int k = lane; k < DIM; k += 64) {
        float xv = xr[k];
#pragma unroll
        for (int e = 0; e < NE; e++) s[e] += xv * gw[e * DIM + k];
    }
#pragma unroll
    for (int e = 0; e < NE; e++) {
#pragma unroll
        for (int off = 32; off >= 1; off >>= 1) s[e] += __shfl_xor(s[e], off, 64);
    }
    if (lane == 0) {
        float mx = s[0];
#pragma unroll
        for (int e = 1; e < NE; e++) mx = fmaxf(mx, s[e]);
        float p[NE]; float den = 0.f;
#pragma unroll
        for (int e = 0; e < NE; e++) { p[e] = __expf(s[e] - mx); den += p[e]; }
        float inv = 1.f / den;
        int i0 = 0, i1 = -1; float b0 = p[0], b1 = -1.f;
#pragma unroll
        for (int e = 1; e < NE; e++) {
            float v = p[e];
            if (v > b0) { b1 = b0; i1 = i0; b0 = v; i0 = e; }
            else if (v > b1) { b1 = v; i1 = e; }
        }
        tk_idx[tok * 2] = i0;     tk_idx[tok * 2 + 1] = i1;
        tk_w[tok * 2] = b0 * inv; tk_w[tok * 2 + 1] = b1 * inv;
        atomicAdd(&cnt[i0], 1);   atomicAdd(&cnt[i1], 1);
    }
}

// ---------------- prefix offsets (16 segments incl. shared) ----------------
__global__ void offsets_kernel(int* __restrict__ cnt, int* __restrict__ off) {
    if (threadIdx.x == 0 && blockIdx.x == 0) {
        int a = 0;
        for (int e = 0; e < NE; e++) { off[e] = a; a += cnt[e]; }
        off[NE] = NROUTED;      // shared segment starts at 8192
        cnt[NE] = T_TOKENS;     // shared expert gets every token
    }
}

// ---------------- scatter tokens into slots ----------------
__global__ void scatter_kernel(const int* __restrict__ tk_idx, const float* __restrict__ tk_w,
                               const int* __restrict__ off, int* __restrict__ fill,
                               int* __restrict__ rows, float* __restrict__ rwt) {
    int id = blockIdx.x * 256 + threadIdx.x;
    if (id < NROUTED) {
        int e = tk_idx[id];
        int pos = off[e] + atomicAdd(&fill[e], 1);
        rows[pos] = id >> 1;
        rwt[pos] = tk_w[id];
    } else if (id < NSLOT) {
        int t = id - NROUTED;
        rows[NROUTED + t] = t;
        rwt[NROUTED + t] = 1.0f;
    }
}

// ================= NEW PATH: all-bf16 GEMMs with global_load_lds =================

// GEMM1: H = silu(X w1^T) * (X w3^T), bf16 weights, m97-style staging
__global__ __launch_bounds__(256, 2)
void gemm1b_kernel(const unsigned short* __restrict__ xb,
                   const unsigned short* __restrict__ w1b,
                   const unsigned short* __restrict__ w3b,
                   const unsigned short* __restrict__ sw1b,
                   const unsigned short* __restrict__ sw3b,
                   const int* __restrict__ rows, const int* __restrict__ off,
                   const int* __restrict__ cnt,
                   unsigned short* __restrict__ Ha) {
    __shared__ __align__(16) unsigned short As[128 * 32];
    __shared__ __align__(16) unsigned short B1s[128 * 32];
    __shared__ __align__(16) unsigned short B3s[128 * 32];
    __shared__ int rowLds[128];

    const int e = blockIdx.z;
    const int count = cnt[e];
    const int m0 = blockIdx.y * 128;
    if (m0 >= count) return;
    const int base = off[e];
    const int n0 = blockIdx.x * 128;

    const unsigned short* W1 = ((e < NE) ? (w1b + (size_t)e * INTER * DIM) : sw1b) + (size_t)n0 * DIM;
    const unsigned short* W3 = ((e < NE) ? (w3b + (size_t)e * INTER * DIM) : sw3b) + (size_t)n0 * DIM;

    const int tid = threadIdx.x;
    if (tid < 128) {
        int mi = m0 + tid;
        rowLds[tid] = rows[base + ((mi < count) ? mi : 0)];
    }
    __syncthreads();

    const int wave = tid >> 6, lane = tid & 63;
    // staging geometry: wave w covers tile rows [w*16, w*16+16) (+64 for 2nd instr)
    const int srow = wave * 16 + (lane >> 2);   // 0..63
    const int scol = (lane & 3) * 8;            // 8 bf16 = 16B per lane
    const unsigned short* a_src0  = xb + (size_t)rowLds[srow] * DIM + scol;
    const unsigned short* a_src1  = xb + (size_t)rowLds[srow + 64] * DIM + scol;
    const unsigned short* b1_src0 = W1 + (size_t)srow * DIM + scol;
    const unsigned short* b1_src1 = W1 + (size_t)(srow + 64) * DIM + scol;
    const unsigned short* b3_src0 = W3 + (size_t)srow * DIM + scol;
    const unsigned short* b3_src1 = W3 + (size_t)(srow + 64) * DIM + scol;
    unsigned short* a_dst0  = As  + wave * 512;         // 16 rows * 32 shorts
    unsigned short* a_dst1  = As  + 2048 + wave * 512;
    unsigned short* b1_dst0 = B1s + wave * 512;
    unsigned short* b1_dst1 = B1s + 2048 + wave * 512;
    unsigned short* b3_dst0 = B3s + wave * 512;
    unsigned short* b3_dst1 = B3s + 2048 + wave * 512;

    const int wm = (wave >> 1) * 64, wn = (wave & 1) * 64;
    const int lr = lane & 15, lq = lane >> 4;
    const unsigned short* afp  = As  + (wm + lr) * 32 + lq * 8;
    const unsigned short* b1fp = B1s + (wn + lr) * 32 + lq * 8;
    const unsigned short* b3fp = B3s + (wn + lr) * 32 + lq * 8;

    f32x4 acc1[16], acc3[16];
    const f32x4 fz = {0.f, 0.f, 0.f, 0.f};
#pragma unroll
    for (int i = 0; i < 16; i++) { acc1[i] = fz; acc3[i] = fz; }

    for (int kt = 0; kt < DIM / 32; ++kt) {
        gll16(a_src0, a_dst0);   gll16(a_src1, a_dst1);
        gll16(b1_src0, b1_dst0); gll16(b1_src1, b1_dst1);
        gll16(b3_src0, b3_dst0); gll16(b3_src1, b3_dst1);
        a_src0 += 32; a_src1 += 32;
        b1_src0 += 32; b1_src1 += 32;
        b3_src0 += 32; b3_src1 += 32;
        __syncthreads();   // vmcnt(0) drain -> tiles resident
        short8 af[4], b1f[4], b3f[4];
#pragma unroll
        for (int i = 0; i < 4; i++) af[i] = *(const short8*)(afp + i * 16 * 32);
#pragma unroll
        for (int j = 0; j < 4; j++) {
            b1f[j] = *(const short8*)(b1fp + j * 16 * 32);
            b3f[j] = *(const short8*)(b3fp + j * 16 * 32);
        }
#pragma unroll
        for (int i = 0; i < 4; i++)
#pragma unroll
            for (int j = 0; j < 4; j++) {
                acc1[i * 4 + j] = __builtin_amdgcn_mfma_f32_16x16x32_bf16(af[i], b1f[j], acc1[i * 4 + j], 0, 0, 0);
                acc3[i * 4 + j] = __builtin_amdgcn_mfma_f32_16x16x32_bf16(af[i], b3f[j], acc3[i * 4 + j], 0, 0, 0);
            }
        __syncthreads();   // reads done before next-stage overwrite
    }

    // fused SiLU epilogue -> Ha (bf16)
#pragma unroll
    for (int i = 0; i < 4; i++) {
#pragma unroll
        for (int t = 0; t < 4; t++) {
            int lm = wm + i * 16 + lq * 4 + t;
            int mi = m0 + lm;
            if (mi < count) {
                size_t rowbase = (size_t)(base + mi) * INTER + n0 + wn + lr;
#pragma unroll
                for (int j = 0; j < 4; j++) {
                    float h1 = acc1[i * 4 + j][t];
                    float h3 = acc3[i * 4 + j][t];
                    float hv = h1 / (1.f + __expf(-h1)) * h3;
                    Ha[rowbase + j * 16] = f2bf(hv);
                }
            }
        }
    }
}

// GEMM2: out += rwt * (H w2^T), bf16 weights, m97-style staging
__global__ __launch_bounds__(256, 3)
void gemm2b_kernel(const unsigned short* __restrict__ Ha,
                   const unsigned short* __restrict__ w2b,
                   const unsigned short* __restrict__ sw2b,
                   const int* __restrict__ rows, const float* __restrict__ rwt,
                   const int* __restrict__ off, const int* __restrict__ cnt,
                   float* __restrict__ out) {
    __shared__ __align__(16) unsigned short As[128 * 32];
    __shared__ __align__(16) unsigned short Bs[128 * 32];
    __shared__ int tokLds[128];
    __shared__ float wtLds[128];

    const int e = blockIdx.z;
    const int count = cnt[e];
    const int m0 = blockIdx.y * 128;
    if (m0 >= count) return;
    const int base = off[e];
    const int n0 = blockIdx.x * 128;
    const int s0 = base + m0;

    const unsigned short* W2 = ((e < NE) ? (w2b + (size_t)e * DIM * INTER) : sw2b) + (size_t)n0 * INTER;

    const int tid = threadIdx.x;
    if (tid < 128) {
        tokLds[tid] = rows[s0 + tid];
        wtLds[tid] = rwt[s0 + tid];
    }

    const int wave = tid >> 6, lane = tid & 63;
    const int srow = wave * 16 + (lane >> 2);
    const int scol = (lane & 3) * 8;
    const unsigned short* a_src0 = Ha + (size_t)(s0 + srow) * INTER + scol;
    const unsigned short* a_src1 = Ha + (size_t)(s0 + srow + 64) * INTER + scol;
    const unsigned short* b_src0 = W2 + (size_t)srow * INTER + scol;
    const unsigned short* b_src1 = W2 + (size_t)(srow + 64) * INTER + scol;
    unsigned short* a_dst0 = As + wave * 512;
    unsigned short* a_dst1 = As + 2048 + wave * 512;
    unsigned short* b_dst0 = Bs + wave * 512;
    unsigned short* b_dst1 = Bs + 2048 + wave * 512;

    const int wm = (wave >> 1) * 64, wn = (wave & 1) * 64;
    const int lr = lane & 15, lq = lane >> 4;
    const unsigned short* afp = As + (wm + lr) * 32 + lq * 8;
    const unsigned short* bfp = Bs + (wn + lr) * 32 + lq * 8;

    f32x4 acc[16];
    const f32x4 fz = {0.f, 0.f, 0.f, 0.f};
#pragma unroll
    for (int i = 0; i < 16; i++) acc[i] = fz;

    __syncthreads();   // tokLds/wtLds + first-stage ordering

    for (int kt = 0; kt < INTER / 32; ++kt) {
        gll16(a_src0, a_dst0); gll16(a_src1, a_dst1);
        gll16(b_src0, b_dst0); gll16(b_src1, b_dst1);
        a_src0 += 32; a_src1 += 32; b_src0 += 32; b_src1 += 32;
        __syncthreads();
        short8 af[4], bf_[4];
#pragma unroll
        for (int i = 0; i < 4; i++) af[i] = *(const short8*)(afp + i * 16 * 32);
#pragma unroll
        for (int j = 0; j < 4; j++) bf_[j] = *(const short8*)(bfp + j * 16 * 32);
#pragma unroll
        for (int i = 0; i < 4; i++)
#pragma unroll
            for (int j = 0; j < 4; j++)
                acc[i * 4 + j] = __builtin_amdgcn_mfma_f32_16x16x32_bf16(af[i], bf_[j], acc[i * 4 + j], 0, 0, 0);
        __syncthreads();
    }

#pragma unroll
    for (int i = 0; i < 4; i++) {
#pragma unroll
        for (int t = 0; t < 4; t++) {
            int lm = wm + i * 16 + lq * 4 + t;
            int mi = m0 + lm;
            if (mi < count) {
                float wgt = wtLds[lm];
                float* orow = out + (size_t)tokLds[lm] * DIM + n0 + wn + lr;
#pragma unroll
                for (int j = 0; j < 4; j++)
                    atomicAdd(orow + j * 16, acc[i * 4 + j][t] * wgt);
            }
        }
    }
}

// ================= OLD PATH (fp32 weights, reg-staged) — workspace fallback =================

__global__ __launch_bounds__(256, 2)
void gemm1_kernel(const unsigned short* __restrict__ xb,
                  const float* __restrict__ w1, const float* __restrict__ w3,
                  const float* __restrict__ sw1, const float* __restrict__ sw3,
                  const int* __restrict__ rows, const int* __restrict__ off,
                  const int* __restrict__ cnt,
                  unsigned short* __restrict__ Ha) {
    __shared__ unsigned short As[128 * 32];
    __shared__ unsigned short B1s[128 * 32];
    __shared__ unsigned short B3s[128 * 32];
    __shared__ int rowLds[128];

    const int e = blockIdx.z;
    const int count = cnt[e];
    const int m0 = blockIdx.y * 128;
    if (m0 >= count) return;
    const int base = off[e];
    const int n0 = blockIdx.x * 128;

    const float* W1 = ((e < NE) ? (w1 + (size_t)e * INTER * DIM) : sw1) + (size_t)n0 * DIM;
    const float* W3 = ((e < NE) ? (w3 + (size_t)e * INTER * DIM) : sw3) + (size_t)n0 * DIM;

    const int tid = threadIdx.x;
    if (tid < 128) {
        int mi = m0 + tid;
        rowLds[tid] = rows[base + ((mi < count) ? mi : 0)];
    }
    __syncthreads();

    const int ar0 = tid >> 2, seg = tid & 3;
    const uint4* ap0 = (const uint4*)(xb + (size_t)rowLds[ar0] * DIM) + seg;
    const uint4* ap1 = (const uint4*)(xb + (size_t)rowLds[ar0 + 64] * DIM) + seg;
    const float4* b1p0 = (const float4*)(W1 + (size_t)ar0 * DIM) + seg * 2;
    const float4* b1p1 = (const float4*)(W1 + (size_t)(ar0 + 64) * DIM) + seg * 2;
    const float4* b3p0 = (const float4*)(W3 + (size_t)ar0 * DIM) + seg * 2;
    const float4* b3p1 = (const float4*)(W3 + (size_t)(ar0 + 64) * DIM) + seg * 2;

    uint4* aw0 = (uint4*)As + ar0 * 4 + seg;
    uint4* aw1 = (uint4*)As + (ar0 + 64) * 4 + seg;
    uint4* b1w0 = (uint4*)B1s + ar0 * 4 + seg;
    uint4* b1w1 = (uint4*)B1s + (ar0 + 64) * 4 + seg;
    uint4* b3w0 = (uint4*)B3s + ar0 * 4 + seg;
    uint4* b3w1 = (uint4*)B3s + (ar0 + 64) * 4 + seg;

    const int wave = tid >> 6, lane = tid & 63;
    const int wm = (wave >> 1) * 64, wn = (wave & 1) * 64;
    const int lr = lane & 15, lq = lane >> 4;
    const unsigned short* afp  = As  + (wm + lr) * 32 + lq * 8;
    const unsigned short* b1fp = B1s + (wn + lr) * 32 + lq * 8;
    const unsigned short* b3fp = B3s + (wn + lr) * 32 + lq * 8;

    f32x4 acc1[16], acc3[16];
    const f32x4 fz = {0.f, 0.f, 0.f, 0.f};
#pragma unroll
    for (int i = 0; i < 16; i++) { acc1[i] = fz; acc3[i] = fz; }

    for (int kt = 0; kt < DIM / 32; ++kt) {
        uint4 av0 = ap0[0], av1 = ap1[0];
        float4 f10a = b1p0[0], f10b = b1p0[1];
        float4 f11a = b1p1[0], f11b = b1p1[1];
        float4 f30a = b3p0[0], f30b = b3p0[1];
        float4 f31a = b3p1[0], f31b = b3p1[1];
        ap0 += 4; ap1 += 4;
        b1p0 += 8; b1p1 += 8; b3p0 += 8; b3p1 += 8;
        __syncthreads();
        *aw0 = av0; *aw1 = av1;
        *b1w0 = cvt8(f10a, f10b); *b1w1 = cvt8(f11a, f11b);
        *b3w0 = cvt8(f30a, f30b); *b3w1 = cvt8(f31a, f31b);
        __syncthreads();
        short8 af[4], b1f[4], b3f[4];
#pragma unroll
        for (int i = 0; i < 4; i++) af[i] = *(const short8*)(afp + i * 16 * 32);
#pragma unroll
        for (int j = 0; j < 4; j++) {
            b1f[j] = *(const short8*)(b1fp + j * 16 * 32);
            b3f[j] = *(const short8*)(b3fp + j * 16 * 32);
        }
#pragma unroll
        for (int i = 0; i < 4; i++)
#pragma unroll
            for (int j = 0; j < 4; j++) {
                acc1[i * 4 + j] = __builtin_amdgcn_mfma_f32_16x16x32_bf16(af[i], b1f[j], acc1[i * 4 + j], 0, 0, 0);
                acc3[i * 4 + j] = __builtin_amdgcn_mfma_f32_16x16x32_bf16(af[i], b3f[j], acc3[i * 4 + j], 0, 0, 0);
            }
    }

#pragma unroll
    for (int i = 0; i < 4; i++) {
#pragma unroll
        for (int t = 0; t < 4; t++) {
            int lm = wm + i * 16 + lq * 4 + t;
            int mi = m0 + lm;
            if (mi < count) {
                size_t rowbase = (size_t)(base + mi) * INTER + n0 + wn + lr;
#pragma unroll
                for (int j = 0; j < 4; j++) {
                    float h1 = acc1[i * 4 + j][t];
                    float h3 = acc3[i * 4 + j][t];
                    float hv = h1 / (1.f + __expf(-h1)) * h3;
                    Ha[rowbase + j * 16] = f2bf(hv);
                }
            }
        }
    }
}

__global__ __launch_bounds__(256, 2)
void gemm2_kernel(const unsigned short* __restrict__ Ha,
                  const float* __restrict__ w2, const float* __restrict__ sw2,
                  const int* __restrict__ rows, const float* __restrict__ rwt,
                  const int* __restrict__ off, const int* __restrict__ cnt,
                  float* __restrict__ out) {
    __shared__ unsigned short As[128 * 32];
    __shared__ unsigned short Bs[128 * 32];
    __shared__ int tokLds[128];
    __shared__ float wtLds[128];

    const int e = blockIdx.z;
    const int count = cnt[e];
    const int m0 = blockIdx.y * 128;
    if (m0 >= count) return;
    const int base = off[e];
    const int n0 = blockIdx.x * 128;
    const int s0 = base + m0;

    const float* W2 = ((e < NE) ? (w2 + (size_t)e * DIM * INTER) : sw2) + (size_t)n0 * INTER;

    const int tid = threadIdx.x;
    if (tid < 128) {
        tokLds[tid] = rows[s0 + tid];
        wtLds[tid] = rwt[s0 + tid];
    }

    const int ar0 = tid >> 2, seg = tid & 3;
    const uint4* ap0 = (const uint4*)(Ha + (size_t)(s0 + ar0) * INTER) + seg;
    const uint4* ap1 = (const uint4*)(Ha + (size_t)(s0 + ar0 + 64) * INTER) + seg;
    const float4* bp0 = (const float4*)(W2 + (size_t)ar0 * INTER) + seg * 2;
    const float4* bp1 = (const float4*)(W2 + (size_t)(ar0 + 64) * INTER) + seg * 2;
    uint4* aw0 = (uint4*)As + ar0 * 4 + seg;
    uint4* aw1 = (uint4*)As + (ar0 + 64) * 4 + seg;
    uint4* bw0 = (uint4*)Bs + ar0 * 4 + seg;
    uint4* bw1 = (uint4*)Bs + (ar0 + 64) * 4 + seg;

    const int wave = tid >> 6, lane = tid & 63;
    const int wm = (wave >> 1) * 64, wn = (wave & 1) * 64;
    const int lr = lane & 15, lq = lane >> 4;
    const unsigned short* afp = As + (wm + lr) * 32 + lq * 8;
    const unsigned short* bfp = Bs + (wn + lr) * 32 + lq * 8;

    f32x4 acc[16];
    const f32x4 fz = {0.f, 0.f, 0.f, 0.f};
#pragma unroll
    for (int i = 0; i < 16; i++) acc[i] = fz;

    for (int kt = 0; kt < INTER / 32; ++kt) {
        uint4 av0 = ap0[0], av1 = ap1[0];
        float4 f0a = bp0[0], f0b = bp0[1];
        float4 f1a = bp1[0], f1b = bp1[1];
        ap0 += 4; ap1 += 4; bp0 += 8; bp1 += 8;
        __syncthreads();
        *aw0 = av0; *aw1 = av1;
        *bw0 = cvt8(f0a, f0b); *bw1 = cvt8(f1a, f1b);
        __syncthreads();
        short8 af[4], bf_[4];
#pragma unroll
        for (int i = 0; i < 4; i++) af[i] = *(const short8*)(afp + i * 16 * 32);
#pragma unroll
        for (int j = 0; j < 4; j++) bf_[j] = *(const short8*)(bfp + j * 16 * 32);
#pragma unroll
        for (int i = 0; i < 4; i++)
#pragma unroll
            for (int j = 0; j < 4; j++)
                acc[i * 4 + j] = __builtin_amdgcn_mfma_f32_16x16x32_bf16(af[i], bf_[j], acc[i * 4 + j], 0, 0, 0);
    }

#pragma unroll
    for (int i = 0; i < 4; i++) {
#pragma unroll
        for (int t = 0; t < 4; t++) {
            int lm = wm + i * 16 + lq * 4 + t;
            int mi = m0 + lm;
            if (mi < count) {
                float wgt = wtLds[lm];
                float* orow = out + (size_t)tokLds[lm] * DIM + n0 + wn + lr;
#pragma unroll
                for (int j = 0; j < 4; j++)
                    atomicAdd(orow + j * 16, acc[i * 4 + j][t] * wgt);
            }
        }
    }
}

extern "C" void kernel_launch(void* const* d_in, const int* in_sizes, int n_in,
                              void* d_out, int out_size, void* d_ws, size_t ws_size,
                              hipStream_t stream) {
    const float* x   = (const float*)d_in[0];
    const float* gw  = (const float*)d_in[1];
    const float* w1  = (const float*)d_in[2];
    const float* w3  = (const float*)d_in[3];
    const float* w2  = (const float*)d_in[4];
    const float* sw1 = (const float*)d_in[5];
    const float* sw3 = (const float*)d_in[6];
    const float* sw2 = (const float*)d_in[7];
    float* out = (float*)d_out;

    char* p = (char*)d_ws;
    // small control buffers first (shared by both paths)
    int*   rows   = (int*)p;   p += NSLOT * 4;
    float* rwt    = (float*)p; p += NSLOT * 4;
    int*   tk_idx = (int*)p;   p += NROUTED * 4;
    float* tk_w   = (float*)p; p += NROUTED * 4;
    int*   cnt    = (int*)p;   p += 64;
    int*   fill   = (int*)p;   p += 64;
    int*   off    = (int*)p;   p += 64;
    p = (char*)(((size_t)p + 255) & ~(size_t)255);
    unsigned short* xb = (unsigned short*)p; p += (size_t)T_TOKENS * DIM * 2;   // 16.8 MB
    unsigned short* Ha = (unsigned short*)p; p += (size_t)NSLOT * INTER * 2;    // 34.6 MB
    // bf16 weight buffers (new path only)
    unsigned short* w1b  = (unsigned short*)p; p += (size_t)NE * INTER * DIM * 2; // 86.5 MB
    unsigned short* w3b  = (unsigned short*)p; p += (size_t)NE * INTER * DIM * 2;
    unsigned short* w2b  = (unsigned short*)p; p += (size_t)NE * DIM * INTER * 2;
    unsigned short* sw1b = (unsigned short*)p; p += (size_t)INTER * DIM * 2;      // 5.8 MB
    unsigned short* sw3b = (unsigned short*)p; p += (size_t)INTER * DIM * 2;
    unsigned short* sw2b = (unsigned short*)p; p += (size_t)DIM * INTER * 2;
    size_t need = (size_t)(p - (char*)d_ws);

    hipMemsetAsync(cnt, 0, 192, stream);                                   // cnt+fill+off
    hipMemsetAsync(out, 0, (size_t)T_TOKENS * DIM * 4, stream);

    gate_kernel<<<T_TOKENS, 64, 0, stream>>>(x, gw, tk_idx, tk_w, cnt);
    offsets_kernel<<<1, 64, 0, stream>>>(cnt, off);
    scatter_kernel<<<NSLOT / 256, 256, 0, stream>>>(tk_idx, tk_w, off, fill, rows, rwt);

    if (ws_size >= need) {
        // ---- new path: preconvert weights + x to bf16, then all-bf16 GEMMs ----
        const int NR_ELEM = NE * INTER * DIM;        // 43,253,760 (divisible by 2048)
        const int SH_ELEM = INTER * DIM;             // 2,883,584
        cvt_bf16_kernel<<<T_TOKENS * DIM / 2048, 256, 0, stream>>>(x, xb);
        cvt_bf16_kernel<<<NR_ELEM / 2048, 256, 0, stream>>>(w1, w1b);
        cvt_bf16_kernel<<<NR_ELEM / 2048, 256, 0, stream>>>(w3, w3b);
        cvt_bf16_kernel<<<NR_ELEM / 2048, 256, 0, stream>>>(w2, w2b);
        cvt_bf16_kernel<<<SH_ELEM / 2048, 256, 0, stream>>>(sw1, sw1b);
        cvt_bf16_kernel<<<SH_ELEM / 2048, 256, 0, stream>>>(sw3, sw3b);
        cvt_bf16_kernel<<<SH_ELEM / 2048, 256, 0, stream>>>(sw2, sw2b);
        gemm1b_kernel<<<dim3(11, 32, 16), 256, 0, stream>>>(xb, w1b, w3b, sw1b, sw3b, rows, off, cnt, Ha);
        gemm2b_kernel<<<dim3(16, 32, 16), 256, 0, stream>>>(Ha, w2b, sw2b, rows, rwt, off, cnt, out);
    } else {
        // ---- fallback: verified fp32-weight path ----
        cvt_x_kernel<<<8192, 256, 0, stream>>>(x, xb);
        gemm1_kernel<<<dim3(11, 32, 16), 256, 0, stream>>>(xb, w1, w3, sw1, sw3, rows, off, cnt, Ha);
        gemm2_kernel<<<dim3(16, 32, 16), 256, 0, stream>>>(Ha, w2, sw2, rows, rwt, off, cnt, out);
    }
}

// Round 2
// 1054.190 us; speedup vs baseline: 1.0231x; 1.0201x over previous
//
#include <hip/hip_runtime.h>

#define DIM 2048
#define INTER 1408
#define NE 15
#define T_TOKENS 4096
#define NROUTED (T_TOKENS * 2)      // 8192 routed slots
#define NSLOT (NROUTED + T_TOKENS)  // + 4096 shared = 12288

using short8 = __attribute__((ext_vector_type(8))) short;
using f32x4  = __attribute__((ext_vector_type(4))) float;

__device__ inline unsigned short f2bf(float f) {
    return (unsigned short)((__float_as_uint(f) + 0x8000u) >> 16);
}
__device__ inline unsigned pk2bf(unsigned a, unsigned b) {
    // pack two fp32 (bit patterns) -> two bf16 (round-half-up), one v_perm
    return __builtin_amdgcn_perm(b + 0x8000u, a + 0x8000u, 0x07060302u);
}
__device__ inline uint4 cvt8(float4 f0, float4 f1) {
    uint4 r;
    r.x = pk2bf(__float_as_uint(f0.x), __float_as_uint(f0.y));
    r.y = pk2bf(__float_as_uint(f0.z), __float_as_uint(f0.w));
    r.z = pk2bf(__float_as_uint(f1.x), __float_as_uint(f1.y));
    r.w = pk2bf(__float_as_uint(f1.z), __float_as_uint(f1.w));
    return r;
}
// async global->LDS, 16B per lane, dest = wave-uniform base + lane*16
__device__ inline void gll16(const void* g, void* l) {
    __builtin_amdgcn_global_load_lds(
        (const __attribute__((address_space(1))) unsigned int*)g,
        (__attribute__((address_space(3))) unsigned int*)l, 16, 0, 0);
}

// ---------------- generic fp32 -> bf16 (8 elems/thread) ----------------
__global__ void cvt_bf16_kernel(const float* __restrict__ src, unsigned short* __restrict__ dst) {
    size_t i = ((size_t)blockIdx.x * 256 + threadIdx.x) * 8;
    float4 a = *(const float4*)(src + i);
    float4 b = *(const float4*)(src + i + 4);
    *(uint4*)(dst + i) = cvt8(a, b);
}

// ---------------- x -> bf16 (old path) ----------------
__global__ void cvt_x_kernel(const float* __restrict__ x, unsigned short* __restrict__ xb) {
    int i = (blockIdx.x * 256 + threadIdx.x) * 4;
    float4 v = *(const float4*)(x + i);
    ushort4 o;
    o.x = f2bf(v.x); o.y = f2bf(v.y); o.z = f2bf(v.z); o.w = f2bf(v.w);
    *(ushort4*)(xb + i) = o;
}

// ---------------- gating: softmax over 15, top-2 ----------------
__global__ void gate_kernel(const float* __restrict__ x, const float* __restrict__ gw,
                            int* __restrict__ tk_idx, float* __restrict__ tk_w,
                            int* __restrict__ cnt) {
    int tok = blockIdx.x;
    int lane = threadIdx.x; // 64 threads
    const float* xr = x + (size_t)tok * DIM;
    float s[NE];
#pragma unroll
    for (int e = 0; e < NE; e++) s[e] = 0.f;
    for (int k = lane; k < DIM; k += 64) {
        float xv = xr[k];
#pragma unroll
        for (int e = 0; e < NE; e++) s[e] += xv * gw[e * DIM + k];
    }
#pragma unroll
    for (int e = 0; e < NE; e++) {
#pragma unroll
        for (int off = 32; off >= 1; off >>= 1) s[e] += __shfl_xor(s[e], off, 64);
    }
    if (lane == 0) {
        float mx = s[0];
#pragma unroll
        for (int e = 1; e < NE; e++) mx = fmaxf(mx, s[e]);
        float p[NE]; float den = 0.f;
#pragma unroll
        for (int e = 0; e < NE; e++) { p[e] = __expf(s[e] - mx); den += p[e]; }
        float inv = 1.f / den;
        int i0 = 0, i1 = -1; float b0 = p[0], b1 = -1.f;
#pragma unroll
        for (int e = 1; e < NE; e++) {
            float v = p[e];
            if (v > b0) { b1 = b0; i1 = i0; b0 = v; i0 = e; }
            else if (v > b1) { b1 = v; i1 = e; }
        }
        tk_idx[tok * 2] = i0;     tk_idx[tok * 2 + 1] = i1;
        tk_w[tok * 2] = b0 * inv; tk_w[tok * 2 + 1] = b1 * inv;
        atomicAdd(&cnt[i0], 1);   atomicAdd(&cnt[i1], 1);
    }
}

// ---------------- prefix offsets (16 segments incl. shared) ----------------
__global__ void offsets_kernel(int* __restrict__ cnt, int* __restrict__ off) {
    if (threadIdx.x == 0 && blockIdx.x == 0) {
        int a = 0;
        for (int e = 0; e < NE; e++) { off[e] = a; a += cnt[e]; }
        off[NE] = NROUTED;      // shared segment starts at 8192
        cnt[NE] = T_TOKENS;     // shared expert gets every token
    }
}

// ---------------- scatter tokens into slots (+ inverse map) ----------------
__global__ void scatter_kernel(const int* __restrict__ tk_idx, const float* __restrict__ tk_w,
                               const int* __restrict__ off, int* __restrict__ fill,
                               int* __restrict__ rows, float* __restrict__ rwt,
                               int* __restrict__ t2s) {
    int id = blockIdx.x * 256 + threadIdx.x;
    if (id < NROUTED) {
        int e = tk_idx[id];
        int pos = off[e] + atomicAdd(&fill[e], 1);
        rows[pos] = id >> 1;
        rwt[pos] = tk_w[id];
        t2s[id] = pos;
    } else if (id < NSLOT) {
        int t = id - NROUTED;
        rows[NROUTED + t] = t;
        rwt[NROUTED + t] = 1.0f;
    }
}

// ================= bf16 GEMMs with global_load_lds =================

// GEMM1: H = silu(X w1^T) * (X w3^T), bf16 weights, m97-style staging
__global__ __launch_bounds__(256, 2)
void gemm1b_kernel(const unsigned short* __restrict__ xb,
                   const unsigned short* __restrict__ w1b,
                   const unsigned short* __restrict__ w3b,
                   const unsigned short* __restrict__ sw1b,
                   const unsigned short* __restrict__ sw3b,
                   const int* __restrict__ rows, const int* __restrict__ off,
                   const int* __restrict__ cnt,
                   unsigned short* __restrict__ Ha) {
    __shared__ __align__(16) unsigned short As[128 * 32];
    __shared__ __align__(16) unsigned short B1s[128 * 32];
    __shared__ __align__(16) unsigned short B3s[128 * 32];
    __shared__ int rowLds[128];

    const int e = blockIdx.z;
    const int count = cnt[e];
    const int m0 = blockIdx.y * 128;
    if (m0 >= count) return;
    const int base = off[e];
    const int n0 = blockIdx.x * 128;

    const unsigned short* W1 = ((e < NE) ? (w1b + (size_t)e * INTER * DIM) : sw1b) + (size_t)n0 * DIM;
    const unsigned short* W3 = ((e < NE) ? (w3b + (size_t)e * INTER * DIM) : sw3b) + (size_t)n0 * DIM;

    const int tid = threadIdx.x;
    if (tid < 128) {
        int mi = m0 + tid;
        rowLds[tid] = rows[base + ((mi < count) ? mi : 0)];
    }
    __syncthreads();

    const int wave = tid >> 6, lane = tid & 63;
    const int srow = wave * 16 + (lane >> 2);   // 0..63
    const int scol = (lane & 3) * 8;            // 8 bf16 = 16B per lane
    const unsigned short* a_src0  = xb + (size_t)rowLds[srow] * DIM + scol;
    const unsigned short* a_src1  = xb + (size_t)rowLds[srow + 64] * DIM + scol;
    const unsigned short* b1_src0 = W1 + (size_t)srow * DIM + scol;
    const unsigned short* b1_src1 = W1 + (size_t)(srow + 64) * DIM + scol;
    const unsigned short* b3_src0 = W3 + (size_t)srow * DIM + scol;
    const unsigned short* b3_src1 = W3 + (size_t)(srow + 64) * DIM + scol;
    unsigned short* a_dst0  = As  + wave * 512;         // 16 rows * 32 shorts
    unsigned short* a_dst1  = As  + 2048 + wave * 512;
    unsigned short* b1_dst0 = B1s + wave * 512;
    unsigned short* b1_dst1 = B1s + 2048 + wave * 512;
    unsigned short* b3_dst0 = B3s + wave * 512;
    unsigned short* b3_dst1 = B3s + 2048 + wave * 512;

    const int wm = (wave >> 1) * 64, wn = (wave & 1) * 64;
    const int lr = lane & 15, lq = lane >> 4;
    const unsigned short* afp  = As  + (wm + lr) * 32 + lq * 8;
    const unsigned short* b1fp = B1s + (wn + lr) * 32 + lq * 8;
    const unsigned short* b3fp = B3s + (wn + lr) * 32 + lq * 8;

    f32x4 acc1[16], acc3[16];
    const f32x4 fz = {0.f, 0.f, 0.f, 0.f};
#pragma unroll
    for (int i = 0; i < 16; i++) { acc1[i] = fz; acc3[i] = fz; }

    for (int kt = 0; kt < DIM / 32; ++kt) {
        gll16(a_src0, a_dst0);   gll16(a_src1, a_dst1);
        gll16(b1_src0, b1_dst0); gll16(b1_src1, b1_dst1);
        gll16(b3_src0, b3_dst0); gll16(b3_src1, b3_dst1);
        a_src0 += 32; a_src1 += 32;
        b1_src0 += 32; b1_src1 += 32;
        b3_src0 += 32; b3_src1 += 32;
        __syncthreads();   // vmcnt(0) drain -> tiles resident
        short8 af[4], b1f[4], b3f[4];
#pragma unroll
        for (int i = 0; i < 4; i++) af[i] = *(const short8*)(afp + i * 16 * 32);
#pragma unroll
        for (int j = 0; j < 4; j++) {
            b1f[j] = *(const short8*)(b1fp + j * 16 * 32);
            b3f[j] = *(const short8*)(b3fp + j * 16 * 32);
        }
#pragma unroll
        for (int i = 0; i < 4; i++)
#pragma unroll
            for (int j = 0; j < 4; j++) {
                acc1[i * 4 + j] = __builtin_amdgcn_mfma_f32_16x16x32_bf16(af[i], b1f[j], acc1[i * 4 + j], 0, 0, 0);
                acc3[i * 4 + j] = __builtin_amdgcn_mfma_f32_16x16x32_bf16(af[i], b3f[j], acc3[i * 4 + j], 0, 0, 0);
            }
        __syncthreads();   // reads done before next-stage overwrite
    }

    // fused SiLU epilogue -> Ha (bf16)
#pragma unroll
    for (int i = 0; i < 4; i++) {
#pragma unroll
        for (int t = 0; t < 4; t++) {
            int lm = wm + i * 16 + lq * 4 + t;
            int mi = m0 + lm;
            if (mi < count) {
                size_t rowbase = (size_t)(base + mi) * INTER + n0 + wn + lr;
#pragma unroll
                for (int j = 0; j < 4; j++) {
                    float h1 = acc1[i * 4 + j][t];
                    float h3 = acc3[i * 4 + j][t];
                    float hv = h1 / (1.f + __expf(-h1)) * h3;
                    Ha[rowbase + j * 16] = f2bf(hv);
                }
            }
        }
    }
}

// GEMM2: Ys[slot] = rwt[slot] * (H[slot] w2^T)  -- plain stores, no atomics
__global__ __launch_bounds__(256, 2)
void gemm2s_kernel(const unsigned short* __restrict__ Ha,
                   const unsigned short* __restrict__ w2b,
                   const unsigned short* __restrict__ sw2b,
                   const float* __restrict__ rwt,
                   const int* __restrict__ off, const int* __restrict__ cnt,
                   float* __restrict__ Ys) {
    __shared__ __align__(16) unsigned short As[128 * 32];
    __shared__ __align__(16) unsigned short Bs[128 * 32];
    __shared__ float wtLds[128];

    const int e = blockIdx.z;
    const int count = cnt[e];
    const int m0 = blockIdx.y * 128;
    if (m0 >= count) return;
    const int base = off[e];
    const int n0 = blockIdx.x * 128;
    const int s0 = base + m0;

    const unsigned short* W2 = ((e < NE) ? (w2b + (size_t)e * DIM * INTER) : sw2b) + (size_t)n0 * INTER;

    const int tid = threadIdx.x;
    if (tid < 128) wtLds[tid] = rwt[s0 + tid];

    const int wave = tid >> 6, lane = tid & 63;
    const int srow = wave * 16 + (lane >> 2);
    const int scol = (lane & 3) * 8;
    const unsigned short* a_src0 = Ha + (size_t)(s0 + srow) * INTER + scol;
    const unsigned short* a_src1 = Ha + (size_t)(s0 + srow + 64) * INTER + scol;
    const unsigned short* b_src0 = W2 + (size_t)srow * INTER + scol;
    const unsigned short* b_src1 = W2 + (size_t)(srow + 64) * INTER + scol;
    unsigned short* a_dst0 = As + wave * 512;
    unsigned short* a_dst1 = As + 2048 + wave * 512;
    unsigned short* b_dst0 = Bs + wave * 512;
    unsigned short* b_dst1 = Bs + 2048 + wave * 512;

    const int wm = (wave >> 1) * 64, wn = (wave & 1) * 64;
    const int lr = lane & 15, lq = lane >> 4;
    const unsigned short* afp = As + (wm + lr) * 32 + lq * 8;
    const unsigned short* bfp = Bs + (wn + lr) * 32 + lq * 8;

    f32x4 acc[16];
    const f32x4 fz = {0.f, 0.f, 0.f, 0.f};
#pragma unroll
    for (int i = 0; i < 16; i++) acc[i] = fz;

    __syncthreads();   // wtLds + first-stage ordering

    for (int kt = 0; kt < INTER / 32; ++kt) {
        gll16(a_src0, a_dst0); gll16(a_src1, a_dst1);
        gll16(b_src0, b_dst0); gll16(b_src1, b_dst1);
        a_src0 += 32; a_src1 += 32; b_src0 += 32; b_src1 += 32;
        __syncthreads();
        short8 af[4], bf_[4];
#pragma unroll
        for (int i = 0; i < 4; i++) af[i] = *(const short8*)(afp + i * 16 * 32);
#pragma unroll
        for (int j = 0; j < 4; j++) bf_[j] = *(const short8*)(bfp + j * 16 * 32);
#pragma unroll
        for (int i = 0; i < 4; i++)
#pragma unroll
            for (int j = 0; j < 4; j++)
                acc[i * 4 + j] = __builtin_amdgcn_mfma_f32_16x16x32_bf16(af[i], bf_[j], acc[i * 4 + j], 0, 0, 0);
        __syncthreads();
    }

#pragma unroll
    for (int i = 0; i < 4; i++) {
#pragma unroll
        for (int t = 0; t < 4; t++) {
            int lm = wm + i * 16 + lq * 4 + t;
            int mi = m0 + lm;
            if (mi < count) {
                float wgt = wtLds[lm];
                float* yrow = Ys + (size_t)(s0 + lm) * DIM + n0 + wn + lr;
#pragma unroll
                for (int j = 0; j < 4; j++)
                    yrow[j * 16] = acc[i * 4 + j][t] * wgt;
            }
        }
    }
}

// ---------------- combine: out[t] = Ys[s0] + Ys[s1] + Ys[shared_t] ----------------
__global__ void combine_kernel(const float* __restrict__ Ys, const int* __restrict__ t2s,
                               float* __restrict__ out) {
    int t = blockIdx.x;
    int s0 = t2s[2 * t], s1 = t2s[2 * t + 1];
    const float4* y0 = (const float4*)(Ys + (size_t)s0 * DIM);
    const float4* y1 = (const float4*)(Ys + (size_t)s1 * DIM);
    const float4* ysh = (const float4*)(Ys + (size_t)(NROUTED + t) * DIM);
    float4* o = (float4*)(out + (size_t)t * DIM);
#pragma unroll
    for (int it = 0; it < 2; ++it) {
        int i = it * 256 + threadIdx.x;
        float4 a = y0[i], b = y1[i], c = ysh[i];
        float4 r;
        r.x = a.x + b.x + c.x;
        r.y = a.y + b.y + c.y;
        r.z = a.z + b.z + c.z;
        r.w = a.w + b.w + c.w;
        o[i] = r;
    }
}

// ================= OLD PATH (fp32 weights, reg-staged) — workspace fallback =================

__global__ __launch_bounds__(256, 2)
void gemm1_kernel(const unsigned short* __restrict__ xb,
                  const float* __restrict__ w1, const float* __restrict__ w3,
                  const float* __restrict__ sw1, const float* __restrict__ sw3,
                  const int* __restrict__ rows, const int* __restrict__ off,
                  const int* __restrict__ cnt,
                  unsigned short* __restrict__ Ha) {
    __shared__ unsigned short As[128 * 32];
    __shared__ unsigned short B1s[128 * 32];
    __shared__ unsigned short B3s[128 * 32];
    __shared__ int rowLds[128];

    const int e = blockIdx.z;
    const int count = cnt[e];
    const int m0 = blockIdx.y * 128;
    if (m0 >= count) return;
    const int base = off[e];
    const int n0 = blockIdx.x * 128;

    const float* W1 = ((e < NE) ? (w1 + (size_t)e * INTER * DIM) : sw1) + (size_t)n0 * DIM;
    const float* W3 = ((e < NE) ? (w3 + (size_t)e * INTER * DIM) : sw3) + (size_t)n0 * DIM;

    const int tid = threadIdx.x;
    if (tid < 128) {
        int mi = m0 + tid;
        rowLds[tid] = rows[base + ((mi < count) ? mi : 0)];
    }
    __syncthreads();

    const int ar0 = tid >> 2, seg = tid & 3;
    const uint4* ap0 = (const uint4*)(xb + (size_t)rowLds[ar0] * DIM) + seg;
    const uint4* ap1 = (const uint4*)(xb + (size_t)rowLds[ar0 + 64] * DIM) + seg;
    const float4* b1p0 = (const float4*)(W1 + (size_t)ar0 * DIM) + seg * 2;
    const float4* b1p1 = (const float4*)(W1 + (size_t)(ar0 + 64) * DIM) + seg * 2;
    const float4* b3p0 = (const float4*)(W3 + (size_t)ar0 * DIM) + seg * 2;
    const float4* b3p1 = (const float4*)(W3 + (size_t)(ar0 + 64) * DIM) + seg * 2;

    uint4* aw0 = (uint4*)As + ar0 * 4 + seg;
    uint4* aw1 = (uint4*)As + (ar0 + 64) * 4 + seg;
    uint4* b1w0 = (uint4*)B1s + ar0 * 4 + seg;
    uint4* b1w1 = (uint4*)B1s + (ar0 + 64) * 4 + seg;
    uint4* b3w0 = (uint4*)B3s + ar0 * 4 + seg;
    uint4* b3w1 = (uint4*)B3s + (ar0 + 64) * 4 + seg;

    const int wave = tid >> 6, lane = tid & 63;
    const int wm = (wave >> 1) * 64, wn = (wave & 1) * 64;
    const int lr = lane & 15, lq = lane >> 4;
    const unsigned short* afp  = As  + (wm + lr) * 32 + lq * 8;
    const unsigned short* b1fp = B1s + (wn + lr) * 32 + lq * 8;
    const unsigned short* b3fp = B3s + (wn + lr) * 32 + lq * 8;

    f32x4 acc1[16], acc3[16];
    const f32x4 fz = {0.f, 0.f, 0.f, 0.f};
#pragma unroll
    for (int i = 0; i < 16; i++) { acc1[i] = fz; acc3[i] = fz; }

    for (int kt = 0; kt < DIM / 32; ++kt) {
        uint4 av0 = ap0[0], av1 = ap1[0];
        float4 f10a = b1p0[0], f10b = b1p0[1];
        float4 f11a = b1p1[0], f11b = b1p1[1];
        float4 f30a = b3p0[0], f30b = b3p0[1];
        float4 f31a = b3p1[0], f31b = b3p1[1];
        ap0 += 4; ap1 += 4;
        b1p0 += 8; b1p1 += 8; b3p0 += 8; b3p1 += 8;
        __syncthreads();
        *aw0 = av0; *aw1 = av1;
        *b1w0 = cvt8(f10a, f10b); *b1w1 = cvt8(f11a, f11b);
        *b3w0 = cvt8(f30a, f30b); *b3w1 = cvt8(f31a, f31b);
        __syncthreads();
        short8 af[4], b1f[4], b3f[4];
#pragma unroll
        for (int i = 0; i < 4; i++) af[i] = *(const short8*)(afp + i * 16 * 32);
#pragma unroll
        for (int j = 0; j < 4; j++) {
            b1f[j] = *(const short8*)(b1fp + j * 16 * 32);
            b3f[j] = *(const short8*)(b3fp + j * 16 * 32);
        }
#pragma unroll
        for (int i = 0; i < 4; i++)
#pragma unroll
            for (int j = 0; j < 4; j++) {
                acc1[i * 4 + j] = __builtin_amdgcn_mfma_f32_16x16x32_bf16(af[i], b1f[j], acc1[i * 4 + j], 0, 0, 0);
                acc3[i * 4 + j] = __builtin_amdgcn_mfma_f32_16x16x32_bf16(af[i], b3f[j], acc3[i * 4 + j], 0, 0, 0);
            }
    }

#pragma unroll
    for (int i = 0; i < 4; i++) {
#pragma unroll
        for (int t = 0; t < 4; t++) {
            int lm = wm + i * 16 + lq * 4 + t;
            int mi = m0 + lm;
            if (mi < count) {
                size_t rowbase = (size_t)(base + mi) * INTER + n0 + wn + lr;
#pragma unroll
                for (int j = 0; j < 4; j++) {
                    float h1 = acc1[i * 4 + j][t];
                    float h3 = acc3[i * 4 + j][t];
                    float hv = h1 / (1.f + __expf(-h1)) * h3;
                    Ha[rowbase + j * 16] = f2bf(hv);
                }
            }
        }
    }
}

__global__ __launch_bounds__(256, 2)
void gemm2_kernel(const unsigned short* __restrict__ Ha,
                  const float* __restrict__ w2, const float* __restrict__ sw2,
                  const int* __restrict__ rows, const float* __restrict__ rwt,
                  const int* __restrict__ off, const int* __restrict__ cnt,
                  float* __restrict__ out) {
    __shared__ unsigned short As[128 * 32];
    __shared__ unsigned short Bs[128 * 32];
    __shared__ int tokLds[128];
    __shared__ float wtLds[128];

    const int e = blockIdx.z;
    const int count = cnt[e];
    const int m0 = blockIdx.y * 128;
    if (m0 >= count) return;
    const int base = off[e];
    const int n0 = blockIdx.x * 128;
    const int s0 = base + m0;

    const float* W2 = ((e < NE) ? (w2 + (size_t)e * DIM * INTER) : sw2) + (size_t)n0 * INTER;

    const int tid = threadIdx.x;
    if (tid < 128) {
        tokLds[tid] = rows[s0 + tid];
        wtLds[tid] = rwt[s0 + tid];
    }

    const int ar0 = tid >> 2, seg = tid & 3;
    const uint4* ap0 = (const uint4*)(Ha + (size_t)(s0 + ar0) * INTER) + seg;
    const uint4* ap1 = (const uint4*)(Ha + (size_t)(s0 + ar0 + 64) * INTER) + seg;
    const float4* bp0 = (const float4*)(W2 + (size_t)ar0 * INTER) + seg * 2;
    const float4* bp1 = (const float4*)(W2 + (size_t)(ar0 + 64) * INTER) + seg * 2;
    uint4* aw0 = (uint4*)As + ar0 * 4 + seg;
    uint4* aw1 = (uint4*)As + (ar0 + 64) * 4 + seg;
    uint4* bw0 = (uint4*)Bs + ar0 * 4 + seg;
    uint4* bw1 = (uint4*)Bs + (ar0 + 64) * 4 + seg;

    const int wave = tid >> 6, lane = tid & 63;
    const int wm = (wave >> 1) * 64, wn = (wave & 1) * 64;
    const int lr = lane & 15, lq = lane >> 4;
    const unsigned short* afp = As + (wm + lr) * 32 + lq * 8;
    const unsigned short* bfp = Bs + (wn + lr) * 32 + lq * 8;

    f32x4 acc[16];
    const f32x4 fz = {0.f, 0.f, 0.f, 0.f};
#pragma unroll
    for (int i = 0; i < 16; i++) acc[i] = fz;

    for (int kt = 0; kt < INTER / 32; ++kt) {
        uint4 av0 = ap0[0], av1 = ap1[0];
        float4 f0a = bp0[0], f0b = bp0[1];
        float4 f1a = bp1[0], f1b = bp1[1];
        ap0 += 4; ap1 += 4; bp0 += 8; bp1 += 8;
        __syncthreads();
        *aw0 = av0; *aw1 = av1;
        *bw0 = cvt8(f0a, f0b); *bw1 = cvt8(f1a, f1b);
        __syncthreads();
        short8 af[4], bf_[4];
#pragma unroll
        for (int i = 0; i < 4; i++) af[i] = *(const short8*)(afp + i * 16 * 32);
#pragma unroll
        for (int j = 0; j < 4; j++) bf_[j] = *(const short8*)(bfp + j * 16 * 32);
#pragma unroll
        for (int i = 0; i < 4; i++)
#pragma unroll
            for (int j = 0; j < 4; j++)
                acc[i * 4 + j] = __builtin_amdgcn_mfma_f32_16x16x32_bf16(af[i], bf_[j], acc[i * 4 + j], 0, 0, 0);
    }

#pragma unroll
    for (int i = 0; i < 4; i++) {
#pragma unroll
        for (int t = 0; t < 4; t++) {
            int lm = wm + i * 16 + lq * 4 + t;
            int mi = m0 + lm;
            if (mi < count) {
                float wgt = wtLds[lm];
                float* orow = out + (size_t)tokLds[lm] * DIM + n0 + wn + lr;
#pragma unroll
                for (int j = 0; j < 4; j++)
                    atomicAdd(orow + j * 16, acc[i * 4 + j][t] * wgt);
            }
        }
    }
}

extern "C" void kernel_launch(void* const* d_in, const int* in_sizes, int n_in,
                              void* d_out, int out_size, void* d_ws, size_t ws_size,
                              hipStream_t stream) {
    const float* x   = (const float*)d_in[0];
    const float* gw  = (const float*)d_in[1];
    const float* w1  = (const float*)d_in[2];
    const float* w3  = (const float*)d_in[3];
    const float* w2  = (const float*)d_in[4];
    const float* sw1 = (const float*)d_in[5];
    const float* sw3 = (const float*)d_in[6];
    const float* sw2 = (const float*)d_in[7];
    float* out = (float*)d_out;

    char* p = (char*)d_ws;
    // small control buffers first (shared by both paths)
    int*   rows   = (int*)p;   p += NSLOT * 4;
    float* rwt    = (float*)p; p += NSLOT * 4;
    int*   tk_idx = (int*)p;   p += NROUTED * 4;
    float* tk_w   = (float*)p; p += NROUTED * 4;
    int*   t2s    = (int*)p;   p += NROUTED * 4;
    int*   cnt    = (int*)p;   p += 64;
    int*   fill   = (int*)p;   p += 64;
    int*   off    = (int*)p;   p += 64;
    p = (char*)(((size_t)p + 255) & ~(size_t)255);
    unsigned short* xb = (unsigned short*)p; p += (size_t)T_TOKENS * DIM * 2;   // 16.8 MB
    unsigned short* Ha = (unsigned short*)p; p += (size_t)NSLOT * INTER * 2;    // 34.6 MB
    // bf16 weight buffers (new path only)
    unsigned short* w1b  = (unsigned short*)p; p += (size_t)NE * INTER * DIM * 2; // 86.5 MB
    unsigned short* w3b  = (unsigned short*)p; p += (size_t)NE * INTER * DIM * 2;
    unsigned short* w2b  = (unsigned short*)p; p += (size_t)NE * DIM * INTER * 2;
    unsigned short* sw1b = (unsigned short*)p; p += (size_t)INTER * DIM * 2;      // 5.8 MB
    unsigned short* sw3b = (unsigned short*)p; p += (size_t)INTER * DIM * 2;
    unsigned short* sw2b = (unsigned short*)p; p += (size_t)DIM * INTER * 2;
    size_t need = (size_t)(p - (char*)d_ws);
    // Ys aliases w1b..w3b (173 MB region, dead after gemm1b; Ys needs 100.7 MB)
    float* Ys = (float*)w1b;

    hipMemsetAsync(cnt, 0, 192, stream);                                   // cnt+fill+off

    gate_kernel<<<T_TOKENS, 64, 0, stream>>>(x, gw, tk_idx, tk_w, cnt);
    offsets_kernel<<<1, 64, 0, stream>>>(cnt, off);
    scatter_kernel<<<NSLOT / 256, 256, 0, stream>>>(tk_idx, tk_w, off, fill, rows, rwt, t2s);

    if (ws_size >= need) {
        // ---- new path: preconvert to bf16; atomic-free gemm2 via slot buffer + combine ----
        const int NR_ELEM = NE * INTER * DIM;        // 43,253,760 (divisible by 2048)
        const int SH_ELEM = INTER * DIM;             // 2,883,584
        cvt_bf16_kernel<<<T_TOKENS * DIM / 2048, 256, 0, stream>>>(x, xb);
        cvt_bf16_kernel<<<NR_ELEM / 2048, 256, 0, stream>>>(w1, w1b);
        cvt_bf16_kernel<<<NR_ELEM / 2048, 256, 0, stream>>>(w3, w3b);
        cvt_bf16_kernel<<<NR_ELEM / 2048, 256, 0, stream>>>(w2, w2b);
        cvt_bf16_kernel<<<SH_ELEM / 2048, 256, 0, stream>>>(sw1, sw1b);
        cvt_bf16_kernel<<<SH_ELEM / 2048, 256, 0, stream>>>(sw3, sw3b);
        cvt_bf16_kernel<<<SH_ELEM / 2048, 256, 0, stream>>>(sw2, sw2b);
        gemm1b_kernel<<<dim3(11, 32, 16), 256, 0, stream>>>(xb, w1b, w3b, sw1b, sw3b, rows, off, cnt, Ha);
        gemm2s_kernel<<<dim3(16, 32, 16), 256, 0, stream>>>(Ha, w2b, sw2b, rwt, off, cnt, Ys);
        combine_kernel<<<T_TOKENS, 256, 0, stream>>>(Ys, t2s, out);
    } else {
        // ---- fallback: verified fp32-weight path (atomics) ----
        hipMemsetAsync(out, 0, (size_t)T_TOKENS * DIM * 4, stream);
        cvt_x_kernel<<<8192, 256, 0, stream>>>(x, xb);
        gemm1_kernel<<<dim3(11, 32, 16), 256, 0, stream>>>(xb, w1, w3, sw1, sw3, rows, off, cnt, Ha);
        gemm2_kernel<<<dim3(16, 32, 16), 256, 0, stream>>>(Ha, w2, sw2, rows, rwt, off, cnt, out);
    }
}